// Round 14
// baseline (21443.929 us; speedup 1.0000x reference)
//
#include <hip/hip_runtime.h>

// BasicGRU persistent kernel for MI355X (gfx950) — round 14.
//
// R8 skeleton VERBATIM (best measured 14.6ms) + CORRECTED fused
// observe/data-load (R13 fixed):
//
//  Each poll iteration = ONE asm block: flag gather issued FIRST, then the
//  16 data u64 loads, then s_waitcnt vmcnt(16) — waits only for the OLDEST
//  outstanding op (the flag; semantics HW-verified, m135). The flag check
//  runs at flag-RT while data loads fly concurrently; on pass, vmcnt(0)
//  finds them already (mostly) arrived -> the data-load RT hides under the
//  flag observation. On fail: vmcnt(0) drain (prevents VGPR WAR with
//  in-flight loads), s_sleep, re-issue.
//  R13's mistake: data loads BEFORE the flag + vmcnt(0) per iteration ->
//  2-RT iterations -> 20ms. R13 did validate FRESHNESS (absmax unchanged):
//  producer's data-stores -> vmcnt(0) drain -> flag-store margin covers the
//  consumer's flag/data issue skew. Consumption fenced: all 16 u64 tied
//  "+v" into the final waitcnt + sched_barrier(0) (rule 18).
//
// Structure (R8): 8 groups (g=blockIdx&7) x 32 wgs (rank) x 8 batch rows;
//  merged roles: phase1 = r-tile [16r,+16) + z-tile 512+[16r,+16) (shared
//  A-frags; zt + own-h in registers), phase2 = u-tile [16r,+16).
//  h/hr packed u32 (bf16hi<<16|lo), parity double-buffered, relaxed
//  agent-scope (sc0 sc1). Producer: data stores -> vmcnt(0) -> per-wave flag
//  (2t+1/2t+2, 64B apart, waves 0,1). Weights hi bf16 in VGPRs + lo in LDS;
//  3-product bf16-split MFMA. WAR on parity: transitive flag chain.
//
// ws: h2 u32[2][64][512] @0 (256KB); hr2 @262144 (256KB);
//     flags @524288: 8 groups x 64 slots x 64B (32KB). total 557056, memset 0.

#define TT 2048
#define DD 256
#define UU 512

typedef short bf16x8 __attribute__((ext_vector_type(8)));
typedef float f32x4 __attribute__((ext_vector_type(4)));
typedef unsigned int u32;
typedef unsigned long long u64;

#define H2_OFF 0
#define HR2_OFF 262144
#define FLAG_OFF 524288
#define WS_BYTES 557056

__device__ inline unsigned short f2bf(float f) {
  unsigned u = __builtin_bit_cast(unsigned, f);
  u += 0x7FFFu + ((u >> 16) & 1u);  // round-nearest-even
  return (unsigned short)(u >> 16);
}
__device__ inline float bf2f(unsigned short b) {
  unsigned u = ((unsigned)b) << 16;
  return __builtin_bit_cast(float, u);
}
__device__ inline void st_coh_u32(u32* p, u32 v) {
  __hip_atomic_store(p, v, __ATOMIC_RELAXED, __HIP_MEMORY_SCOPE_AGENT);
}

// One fused probe: flag gather FIRST, then 16 data u64 loads, then wait for
// the flag only (vmcnt(16) = oldest op). Data stays in flight.
__device__ inline u32 flag_data_probe(const u32* fp, const u64* db,
                                      u64& q0, u64& q1, u64& q2, u64& q3,
                                      u64& q4, u64& q5, u64& q6, u64& q7,
                                      u64& q8, u64& q9, u64& q10, u64& q11,
                                      u64& q12, u64& q13, u64& q14, u64& q15) {
  u32 f;
  asm volatile(
      "global_load_dword %0, %17, off sc0 sc1\n\t"
      "global_load_dwordx2 %1, %18, off sc0 sc1\n\t"
      "global_load_dwordx2 %2, %18, off offset:8 sc0 sc1\n\t"
      "global_load_dwordx2 %3, %18, off offset:16 sc0 sc1\n\t"
      "global_load_dwordx2 %4, %18, off offset:24 sc0 sc1\n\t"
      "global_load_dwordx2 %5, %18, off offset:512 sc0 sc1\n\t"
      "global_load_dwordx2 %6, %18, off offset:520 sc0 sc1\n\t"
      "global_load_dwordx2 %7, %18, off offset:528 sc0 sc1\n\t"
      "global_load_dwordx2 %8, %18, off offset:536 sc0 sc1\n\t"
      "global_load_dwordx2 %9, %18, off offset:1024 sc0 sc1\n\t"
      "global_load_dwordx2 %10, %18, off offset:1032 sc0 sc1\n\t"
      "global_load_dwordx2 %11, %18, off offset:1040 sc0 sc1\n\t"
      "global_load_dwordx2 %12, %18, off offset:1048 sc0 sc1\n\t"
      "global_load_dwordx2 %13, %18, off offset:1536 sc0 sc1\n\t"
      "global_load_dwordx2 %14, %18, off offset:1544 sc0 sc1\n\t"
      "global_load_dwordx2 %15, %18, off offset:1552 sc0 sc1\n\t"
      "global_load_dwordx2 %16, %18, off offset:1560 sc0 sc1\n\t"
      "s_waitcnt vmcnt(16)"
      : "=&v"(f), "=&v"(q0), "=&v"(q1), "=&v"(q2), "=&v"(q3), "=&v"(q4),
        "=&v"(q5), "=&v"(q6), "=&v"(q7), "=&v"(q8), "=&v"(q9), "=&v"(q10),
        "=&v"(q11), "=&v"(q12), "=&v"(q13), "=&v"(q14), "=&v"(q15)
      : "v"(fp), "v"(db)
      : "memory");
  return f;
}
__device__ inline void drain16(u64& q0, u64& q1, u64& q2, u64& q3, u64& q4,
                               u64& q5, u64& q6, u64& q7, u64& q8, u64& q9,
                               u64& q10, u64& q11, u64& q12, u64& q13,
                               u64& q14, u64& q15) {
  asm volatile("s_waitcnt vmcnt(0)"
               : "+v"(q0), "+v"(q1), "+v"(q2), "+v"(q3), "+v"(q4), "+v"(q5),
                 "+v"(q6), "+v"(q7), "+v"(q8), "+v"(q9), "+v"(q10), "+v"(q11),
                 "+v"(q12), "+v"(q13), "+v"(q14), "+v"(q15)::"memory");
  __builtin_amdgcn_sched_barrier(0);
}

#define MFMA(A, B, C) __builtin_amdgcn_mfma_f32_16x16x32_bf16((A), (B), (C), 0, 0, 0)

__global__ __launch_bounds__(256, 1) void gru_persist(
    const float* __restrict__ x, const float* __restrict__ Wk,
    const float* __restrict__ Wrk, const float* __restrict__ brk,
    const float* __restrict__ Wu, const float* __restrict__ Wur,
    const float* __restrict__ bur, float* __restrict__ out,
    unsigned char* __restrict__ ws) {
  __shared__ short wlo[36864];    // lo weights [3 tiles][24 ch][64 lane][8]
  __shared__ float scratch[2304]; // ph1: r@0 z@1024; ph2: u@0 (+pad -> 83KB)

  const int wgid = blockIdx.x;
  const int g = wgid & 7;         // group (8 batch rows [8g,8g+8))
  const int rank = wgid >> 3;     // 0..31 -> 16-col tile
  const int tid = threadIdx.x;
  const int lane = tid & 63;
  const int wv = tid >> 6;
  const int kgrp = lane >> 4;
  const int c = lane & 15;

  const int C1 = 16 * rank;       // r-gate / u cols
  const int C1z = 512 + C1;       // z-gate cols

  // ---- one-time: hi weight fragments -> VGPRs
  bf16x8 wrhi[6], wzhi[6], wuhi[6];
#pragma unroll
  for (int j = 0; j < 6; ++j) {
    const int kb = 32 * (wv + 4 * j) + kgrp * 8;
#pragma unroll
    for (int i = 0; i < 8; ++i) {
      const int k = kb + i;
      float vr = (k < DD) ? Wk[(size_t)k * 1024 + C1 + c]
                          : Wrk[(size_t)(k - DD) * 1024 + C1 + c];
      float vz = (k < DD) ? Wk[(size_t)k * 1024 + C1z + c]
                          : Wrk[(size_t)(k - DD) * 1024 + C1z + c];
      float vu = (k < DD) ? Wu[(size_t)k * UU + C1 + c]
                          : Wur[(size_t)(k - DD) * UU + C1 + c];
      wrhi[j][i] = (short)f2bf(vr);
      wzhi[j][i] = (short)f2bf(vz);
      wuhi[j][i] = (short)f2bf(vu);
    }
  }
  // ---- one-time: lo weights -> LDS (cooperative; T0=r, T1=z, T2=u)
  for (int idx = tid; idx < 3 * 12288; idx += 256) {
    const int T = idx / 12288;
    const int rem = idx - T * 12288;
    const int k = rem >> 4, cc = rem & 15;
    float v;
    if (T == 0)
      v = (k < DD) ? Wk[(size_t)k * 1024 + C1 + cc]
                   : Wrk[(size_t)(k - DD) * 1024 + C1 + cc];
    else if (T == 1)
      v = (k < DD) ? Wk[(size_t)k * 1024 + C1z + cc]
                   : Wrk[(size_t)(k - DD) * 1024 + C1z + cc];
    else
      v = (k < DD) ? Wu[(size_t)k * UU + C1 + cc]
                   : Wur[(size_t)(k - DD) * UU + C1 + cc];
    unsigned short hb = f2bf(v);
    const int ch = k >> 5, kk = k & 31;
    wlo[((T * 24 + ch) * 64 + (kk >> 3) * 16 + cc) * 8 + (kk & 7)] =
        (short)f2bf(v - bf2f(hb));
  }
  __syncthreads();

  u32* h2 = (u32*)(ws + H2_OFF);    // [2][64 rows][512]
  u32* hr2 = (u32*)(ws + HR2_OFF);  // [2][64 rows][512]
  u32* flg = (u32*)(ws + FLAG_OFF) + (size_t)g * 1024;  // 64 slots x 64B
  u32* myflag = flg + (rank * 2 + wv) * 16;             // used by wv<2 only

  const int bl = tid >> 4, cl = tid & 15;  // reduce coords (bl<8 meaningful)
  const float b_r = brk[C1 + cl];
  const float b_z = brk[C1z + cl];
  const float b_u = bur[C1 + cl];

  const int arow = c & 7;  // A rows 8..15 duplicate 0..7 (C rows 8..15 unused)
  const float* xrow = x + (size_t)(8 * g + arow) * TT * DD;

  bf16x8 xhi[2], xlo[2];
  auto split_x = [&](int t) {
#pragma unroll
    for (int j = 0; j < 2; ++j) {
      const float* p = xrow + (size_t)t * DD + 32 * wv + 128 * j + kgrp * 8;
      f32x4 v0 = *(const f32x4*)p;
      f32x4 v1 = *(const f32x4*)(p + 4);
#pragma unroll
      for (int i = 0; i < 4; ++i) {
        unsigned short hb = f2bf(v0[i]);
        xhi[j][i] = (short)hb;
        xlo[j][i] = (short)f2bf(v0[i] - bf2f(hb));
        unsigned short hb2 = f2bf(v1[i]);
        xhi[j][4 + i] = (short)hb2;
        xlo[j][4 + i] = (short)f2bf(v1[i] - bf2f(hb2));
      }
    }
  };

  // Fused wait+load: probe (flag-first), check, on fail drain+sleep+retry;
  // on pass drain data (already ~arrived) and consume.
  auto poll_ld = [&](u32 need, const u64* dbase, u64* Q) {
    const u32* fp = flg + lane * 16;
    for (;;) {
      u32 f = flag_data_probe(fp, dbase, Q[0], Q[1], Q[2], Q[3], Q[4], Q[5],
                              Q[6], Q[7], Q[8], Q[9], Q[10], Q[11], Q[12],
                              Q[13], Q[14], Q[15]);
      if (__all(f >= need)) break;
      asm volatile("s_waitcnt vmcnt(0)" ::: "memory");  // WAR: drain in-flight
      __builtin_amdgcn_s_sleep(1);
    }
    drain16(Q[0], Q[1], Q[2], Q[3], Q[4], Q[5], Q[6], Q[7], Q[8], Q[9], Q[10],
            Q[11], Q[12], Q[13], Q[14], Q[15]);
  };

  auto chunk3 = [&](const bf16x8& ahi, const bf16x8& alo, const bf16x8& bhi,
                    const bf16x8& blo, f32x4& acc) {
    acc = MFMA(ahi, bhi, acc);
    acc = MFMA(ahi, blo, acc);
    acc = MFMA(alo, bhi, acc);
  };

  split_x(0);
  float hown = 0.f, zt_reg = 0.f;  // own h / update gate (threads tid<128)
  f32x4 ar = {0.f, 0.f, 0.f, 0.f}, az = ar;
#pragma unroll
  for (int j = 0; j < 2; ++j) {  // t=0 x-partials
    bf16x8 br = *(const bf16x8*)&wlo[((wv + 4 * j) * 64 + lane) * 8];
    bf16x8 bz = *(const bf16x8*)&wlo[((24 + wv + 4 * j) * 64 + lane) * 8];
    chunk3(xhi[j], xlo[j], wrhi[j], br, ar);
    chunk3(xhi[j], xlo[j], wzhi[j], bz, az);
  }

  for (int t = 0; t < TT; ++t) {
    // ================= phase 1: fused wait h(t-1)+load; r+z h-part GEMM
    {
      const int bh = (t + 1) & 1;
      const u64* hb = (const u64*)(h2 + ((size_t)(bh * 64 + 8 * g + arow)) * 512 +
                                   32 * wv + kgrp * 8);
      u64 Q[16];
      poll_ld(2 * (u32)t, hb, Q);
#pragma unroll
      for (int p = 0; p < 4; ++p) {
        bf16x8 ahi, alo;
#pragma unroll
        for (int i = 0; i < 4; ++i) {
          u32 lo32 = (u32)Q[4 * p + i], hi32 = (u32)(Q[4 * p + i] >> 32);
          ahi[2 * i] = (short)(lo32 >> 16);
          alo[2 * i] = (short)lo32;
          ahi[2 * i + 1] = (short)(hi32 >> 16);
          alo[2 * i + 1] = (short)hi32;
        }
        const int j = p + 2;
        bf16x8 br = *(const bf16x8*)&wlo[((wv + 4 * j) * 64 + lane) * 8];
        bf16x8 bz = *(const bf16x8*)&wlo[((24 + wv + 4 * j) * 64 + lane) * 8];
        chunk3(ahi, alo, wrhi[j], br, ar);
        chunk3(ahi, alo, wzhi[j], bz, az);
      }
    }
    __syncthreads();  // WAR: prev phase-2 reduce reads done
#pragma unroll
    for (int r = 0; r < 4; ++r) {
      scratch[wv * 256 + (kgrp * 4 + r) * 16 + c] = ar[r];
      scratch[1024 + wv * 256 + (kgrp * 4 + r) * 16 + c] = az[r];
    }
    __syncthreads();
    if (tid < 128) {
      float rv = (scratch[tid] + scratch[256 + tid]) +
                 (scratch[512 + tid] + scratch[768 + tid]) + b_r;
      float zv = (scratch[1024 + tid] + scratch[1280 + tid]) +
                 (scratch[1536 + tid] + scratch[1792 + tid]) + b_z;
      float rg = 1.f / (1.f + __expf(-rv));
      zt_reg = 1.f / (1.f + __expf(-zv));
      float hrv = hown * rg;
      unsigned short hb = f2bf(hrv);
      unsigned short lb = f2bf(hrv - bf2f(hb));
      st_coh_u32(hr2 + ((size_t)((t & 1) * 64 + 8 * g + bl)) * 512 + C1 + cl,
                 ((u32)hb << 16) | lb);
    }
    asm volatile("s_waitcnt vmcnt(0)" ::: "memory");  // drain before flag
    if (wv < 2 && lane == 0) st_coh_u32(myflag, 2 * (u32)t + 1);

    // ================= phase 2: xu pre-GEMM + x(t+1) split, fused wait hr
    f32x4 au = {0.f, 0.f, 0.f, 0.f};
#pragma unroll
    for (int j = 0; j < 2; ++j) {
      bf16x8 bu = *(const bf16x8*)&wlo[((48 + wv + 4 * j) * 64 + lane) * 8];
      chunk3(xhi[j], xlo[j], wuhi[j], bu, au);
    }
    if (t + 1 < TT) split_x(t + 1);
    {
      const u64* hrb = (const u64*)(hr2 + ((size_t)((t & 1) * 64 + 8 * g + arow)) * 512 +
                                    32 * wv + kgrp * 8);
      u64 Q[16];
      poll_ld(2 * (u32)t + 1, hrb, Q);
#pragma unroll
      for (int p = 0; p < 4; ++p) {
        bf16x8 ahi, alo;
#pragma unroll
        for (int i = 0; i < 4; ++i) {
          u32 lo32 = (u32)Q[4 * p + i], hi32 = (u32)(Q[4 * p + i] >> 32);
          ahi[2 * i] = (short)(lo32 >> 16);
          alo[2 * i] = (short)lo32;
          ahi[2 * i + 1] = (short)(hi32 >> 16);
          alo[2 * i + 1] = (short)hi32;
        }
        const int j = p + 2;
        bf16x8 bu = *(const bf16x8*)&wlo[((48 + wv + 4 * j) * 64 + lane) * 8];
        chunk3(ahi, alo, wuhi[j], bu, au);
      }
    }
    __syncthreads();  // WAR: phase-1 reduce reads done
#pragma unroll
    for (int r = 0; r < 4; ++r)
      scratch[wv * 256 + (kgrp * 4 + r) * 16 + c] = au[r];
    __syncthreads();
    if (tid < 128) {
      float uv = (scratch[tid] + scratch[256 + tid]) +
                 (scratch[512 + tid] + scratch[768 + tid]) + b_u;
      float e = __expf(2.f * uv);
      float th = 1.f - 2.f / (e + 1.f);  // tanh(uv)
      float hn = hown + zt_reg * (th - hown);
      hown = hn;
      unsigned short hb = f2bf(hn);
      unsigned short lb = f2bf(hn - bf2f(hb));
      st_coh_u32(h2 + ((size_t)((t & 1) * 64 + 8 * g + bl)) * 512 + C1 + cl,
                 ((u32)hb << 16) | lb);
      if (t == TT - 1) out[(size_t)(8 * g + bl) * UU + C1 + cl] = hn;
    }
    asm volatile("s_waitcnt vmcnt(0)" ::: "memory");  // drain before flag
    if (wv < 2 && lane == 0) st_coh_u32(myflag, 2 * (u32)t + 2);

    // ---- next-step phase-1 x-partials (pre-poll work)
    ar = (f32x4){0.f, 0.f, 0.f, 0.f};
    az = (f32x4){0.f, 0.f, 0.f, 0.f};
    if (t + 1 < TT) {
#pragma unroll
      for (int j = 0; j < 2; ++j) {
        bf16x8 br = *(const bf16x8*)&wlo[((wv + 4 * j) * 64 + lane) * 8];
        bf16x8 bz = *(const bf16x8*)&wlo[((24 + wv + 4 * j) * 64 + lane) * 8];
        chunk3(xhi[j], xlo[j], wrhi[j], br, ar);
        chunk3(xhi[j], xlo[j], wzhi[j], bz, az);
      }
    }
  }
}

extern "C" void kernel_launch(void* const* d_in, const int* in_sizes, int n_in,
                              void* d_out, int out_size, void* d_ws,
                              size_t ws_size, hipStream_t stream) {
  (void)in_sizes; (void)n_in; (void)out_size; (void)ws_size;
  hipMemsetAsync(d_ws, 0, WS_BYTES, stream);  // h(-1)=0, flags=0 (ready @ t=0)
  gru_persist<<<dim3(256), dim3(256), 0, stream>>>(
      (const float*)d_in[0], (const float*)d_in[1], (const float*)d_in[2],
      (const float*)d_in[3], (const float*)d_in[4], (const float*)d_in[5],
      (const float*)d_in[6], (float*)d_out, (unsigned char*)d_ws);
}

// Round 15
// 14570.645 us; speedup vs baseline: 1.4717x; 1.4717x over previous
//
#include <hip/hip_runtime.h>

// BasicGRU persistent kernel for MI355X (gfx950) — round 15 = R8 RESTORED.
//
// R8 is the best measured configuration (14.57 ms). Six single-variable
// attempts to beat it all measured neutral-to-worse:
//   R9  compact flag lines        -> 19.1 ms (16 writers/line convoy)
//   R10 shadow-move loads/MFMAs   -> 15.3 ms
//   R12 fine-grained dep polling  -> 15.25 ms (fan-in is not the cost)
//   R13 fused data-before-flag    -> 20.2 ms (2-RT poll iterations)
//   R14 fused flag-first vmcnt(16)-> 21.4 ms (fail-path drain, same disease)
//   R7/R11 L2-scope (XCD) sync    -> deadlock x2 (retired)
// Structural floor: 2 dependent all-to-all exchange rounds per GRU step x
// 2048 steps; each round = compute/reduce (~1.1us) + store-drain + flag +
// observe + data-load (~3 agent-scope L3 RTs ~= 2.5us) ~= 3.6us -> ~14.7ms,
// matching measurement. The hop latency is hardware; the round count is
// algorithmic; the column split is forced by weight capacity.
//
// Structure: 256 wgs x 256 thr, 1 wg/CU (83KB LDS).
//  - 8 groups (g=blockIdx&7) x 32 wgs (rank=blockIdx>>3), 8 batch rows per
//    group. Merged roles: each wg does r-tile cols [16r,+16) AND z-tile
//    cols 512+[16r,+16) in phase 1 (shared A-fragments), u-tile cols
//    [16r,+16) in phase 2. zt-gate and own-h element stay in registers.
//  - exchange: h/hr packed u32 (bf16hi<<16|lo), parity double-buffered,
//    relaxed agent-scope (sc0 sc1) loads/stores. Producer: data stores ->
//    s_waitcnt vmcnt(0) -> per-WAVE flag (waves 0,1 = the storing waves;
//    monotonic value 2t+1 / 2t+2, 64B apart). Consumer: single 64-lane
//    gather over the group's 64 flag slots + __all, s_sleep(1) backoff.
//  - post-poll path is minimal: 16 coherent u64 chunk loads (batched) ->
//    unpack -> 24 MFMAs -> LDS reduce. x-only MFMAs and split_x(t+1) run
//    BEFORE the polls (hidden in the wait).
//  - WAR on parity buffers: transitive through the flag chain.
//  - weights: hi bf16 in VGPRs (72/wave: r,z,u x 6 chunks), lo bf16 in LDS
//    (3 tiles x 768 x 16 = 73.7KB); 3-product bf16-split MFMA (~1.5e-5 rel).
//
// ws: h2 u32[2][64][512] @0 (256KB); hr2 @262144 (256KB);
//     flags @524288: 8 groups x 64 slots x 64B (32KB). total 557056, memset 0
//     each launch (h(-1)=0, flags=0 == ready @ t=0).

#define TT 2048
#define DD 256
#define UU 512

typedef short bf16x8 __attribute__((ext_vector_type(8)));
typedef float f32x4 __attribute__((ext_vector_type(4)));
typedef unsigned int u32;
typedef unsigned long long u64;

#define H2_OFF 0
#define HR2_OFF 262144
#define FLAG_OFF 524288
#define WS_BYTES 557056

__device__ inline unsigned short f2bf(float f) {
  unsigned u = __builtin_bit_cast(unsigned, f);
  u += 0x7FFFu + ((u >> 16) & 1u);  // round-nearest-even
  return (unsigned short)(u >> 16);
}
__device__ inline float bf2f(unsigned short b) {
  unsigned u = ((unsigned)b) << 16;
  return __builtin_bit_cast(float, u);
}
__device__ inline u32 ld_coh_u32(const u32* p) {
  return __hip_atomic_load(p, __ATOMIC_RELAXED, __HIP_MEMORY_SCOPE_AGENT);
}
__device__ inline u64 ld_coh_u64(const u64* p) {
  return __hip_atomic_load(p, __ATOMIC_RELAXED, __HIP_MEMORY_SCOPE_AGENT);
}
__device__ inline void st_coh_u32(u32* p, u32 v) {
  __hip_atomic_store(p, v, __ATOMIC_RELAXED, __HIP_MEMORY_SCOPE_AGENT);
}

#define MFMA(A, B, C) __builtin_amdgcn_mfma_f32_16x16x32_bf16((A), (B), (C), 0, 0, 0)

__global__ __launch_bounds__(256, 1) void gru_persist(
    const float* __restrict__ x, const float* __restrict__ Wk,
    const float* __restrict__ Wrk, const float* __restrict__ brk,
    const float* __restrict__ Wu, const float* __restrict__ Wur,
    const float* __restrict__ bur, float* __restrict__ out,
    unsigned char* __restrict__ ws) {
  __shared__ short wlo[36864];    // lo weights [3 tiles][24 ch][64 lane][8]
  __shared__ float scratch[2304]; // ph1: r@0 z@1024; ph2: u@0 (+pad -> 83KB)

  const int wgid = blockIdx.x;
  const int g = wgid & 7;         // group (8 batch rows [8g,8g+8))
  const int rank = wgid >> 3;     // 0..31 -> 16-col tile
  const int tid = threadIdx.x;
  const int lane = tid & 63;
  const int wv = tid >> 6;
  const int kgrp = lane >> 4;
  const int c = lane & 15;

  const int C1 = 16 * rank;       // r-gate / u cols
  const int C1z = 512 + C1;       // z-gate cols

  // ---- one-time: hi weight fragments -> VGPRs
  bf16x8 wrhi[6], wzhi[6], wuhi[6];
#pragma unroll
  for (int j = 0; j < 6; ++j) {
    const int kb = 32 * (wv + 4 * j) + kgrp * 8;
#pragma unroll
    for (int i = 0; i < 8; ++i) {
      const int k = kb + i;
      float vr = (k < DD) ? Wk[(size_t)k * 1024 + C1 + c]
                          : Wrk[(size_t)(k - DD) * 1024 + C1 + c];
      float vz = (k < DD) ? Wk[(size_t)k * 1024 + C1z + c]
                          : Wrk[(size_t)(k - DD) * 1024 + C1z + c];
      float vu = (k < DD) ? Wu[(size_t)k * UU + C1 + c]
                          : Wur[(size_t)(k - DD) * UU + C1 + c];
      wrhi[j][i] = (short)f2bf(vr);
      wzhi[j][i] = (short)f2bf(vz);
      wuhi[j][i] = (short)f2bf(vu);
    }
  }
  // ---- one-time: lo weights -> LDS (cooperative; T0=r, T1=z, T2=u)
  for (int idx = tid; idx < 3 * 12288; idx += 256) {
    const int T = idx / 12288;
    const int rem = idx - T * 12288;
    const int k = rem >> 4, cc = rem & 15;
    float v;
    if (T == 0)
      v = (k < DD) ? Wk[(size_t)k * 1024 + C1 + cc]
                   : Wrk[(size_t)(k - DD) * 1024 + C1 + cc];
    else if (T == 1)
      v = (k < DD) ? Wk[(size_t)k * 1024 + C1z + cc]
                   : Wrk[(size_t)(k - DD) * 1024 + C1z + cc];
    else
      v = (k < DD) ? Wu[(size_t)k * UU + C1 + cc]
                   : Wur[(size_t)(k - DD) * UU + C1 + cc];
    unsigned short hb = f2bf(v);
    const int ch = k >> 5, kk = k & 31;
    wlo[((T * 24 + ch) * 64 + (kk >> 3) * 16 + cc) * 8 + (kk & 7)] =
        (short)f2bf(v - bf2f(hb));
  }
  __syncthreads();

  u32* h2 = (u32*)(ws + H2_OFF);    // [2][64 rows][512]
  u32* hr2 = (u32*)(ws + HR2_OFF);  // [2][64 rows][512]
  u32* flg = (u32*)(ws + FLAG_OFF) + (size_t)g * 1024;  // 64 slots x 16 u32
  u32* myflag = flg + (rank * 2 + wv) * 16;             // used by wv<2 only

  const int bl = tid >> 4, cl = tid & 15;  // reduce coords (bl<8 meaningful)
  const float b_r = brk[C1 + cl];
  const float b_z = brk[C1z + cl];
  const float b_u = bur[C1 + cl];

  const int arow = c & 7;  // A rows 8..15 duplicate 0..7 (C rows 8..15 unused)
  const float* xrow = x + (size_t)(8 * g + arow) * TT * DD;

  bf16x8 xhi[2], xlo[2];
  auto split_x = [&](int t) {
#pragma unroll
    for (int j = 0; j < 2; ++j) {
      const float* p = xrow + (size_t)t * DD + 32 * wv + 128 * j + kgrp * 8;
      f32x4 v0 = *(const f32x4*)p;
      f32x4 v1 = *(const f32x4*)(p + 4);
#pragma unroll
      for (int i = 0; i < 4; ++i) {
        unsigned short hb = f2bf(v0[i]);
        xhi[j][i] = (short)hb;
        xlo[j][i] = (short)f2bf(v0[i] - bf2f(hb));
        unsigned short hb2 = f2bf(v1[i]);
        xhi[j][4 + i] = (short)hb2;
        xlo[j][4 + i] = (short)f2bf(v1[i] - bf2f(hb2));
      }
    }
  };

  auto poll = [&](u32 need) {  // all 64 slots of the group >= need
    const u32* p = flg + lane * 16;
    while (!__all(ld_coh_u32(p) >= need)) __builtin_amdgcn_s_sleep(1);
  };

  auto chunk3 = [&](const bf16x8& ahi, const bf16x8& alo, const bf16x8& bhi,
                    const bf16x8& blo, f32x4& acc) {
    acc = MFMA(ahi, bhi, acc);
    acc = MFMA(ahi, blo, acc);
    acc = MFMA(alo, bhi, acc);
  };

  split_x(0);
  float hown = 0.f, zt_reg = 0.f;  // own h / update gate (threads tid<128)
  f32x4 ar = {0.f, 0.f, 0.f, 0.f}, az = ar;
#pragma unroll
  for (int j = 0; j < 2; ++j) {  // t=0 x-partials
    bf16x8 br = *(const bf16x8*)&wlo[((wv + 4 * j) * 64 + lane) * 8];
    bf16x8 bz = *(const bf16x8*)&wlo[((24 + wv + 4 * j) * 64 + lane) * 8];
    chunk3(xhi[0 + j], xlo[0 + j], wrhi[j], br, ar);
    chunk3(xhi[0 + j], xlo[0 + j], wzhi[j], bz, az);
  }

  for (int t = 0; t < TT; ++t) {
    // ================= phase 1: wait h(t-1); r+z h-part GEMM
    poll(2 * (u32)t);
    {
      const int bh = (t + 1) & 1;
      const u64* hb = (const u64*)(h2 + ((size_t)(bh * 64 + 8 * g + arow)) * 512 +
                                   32 * wv + kgrp * 8);
      u64 Q[16];
#pragma unroll
      for (int p = 0; p < 4; ++p) {
        Q[4 * p + 0] = ld_coh_u64(hb + 64 * p + 0);
        Q[4 * p + 1] = ld_coh_u64(hb + 64 * p + 1);
        Q[4 * p + 2] = ld_coh_u64(hb + 64 * p + 2);
        Q[4 * p + 3] = ld_coh_u64(hb + 64 * p + 3);
      }
#pragma unroll
      for (int p = 0; p < 4; ++p) {
        bf16x8 ahi, alo;
#pragma unroll
        for (int i = 0; i < 4; ++i) {
          u32 lo32 = (u32)Q[4 * p + i], hi32 = (u32)(Q[4 * p + i] >> 32);
          ahi[2 * i] = (short)(lo32 >> 16);
          alo[2 * i] = (short)lo32;
          ahi[2 * i + 1] = (short)(hi32 >> 16);
          alo[2 * i + 1] = (short)hi32;
        }
        const int j = p + 2;
        bf16x8 br = *(const bf16x8*)&wlo[((wv + 4 * j) * 64 + lane) * 8];
        bf16x8 bz = *(const bf16x8*)&wlo[((24 + wv + 4 * j) * 64 + lane) * 8];
        chunk3(ahi, alo, wrhi[j], br, ar);
        chunk3(ahi, alo, wzhi[j], bz, az);
      }
    }
    __syncthreads();  // WAR: prev phase-2 reduce reads done
#pragma unroll
    for (int r = 0; r < 4; ++r) {
      scratch[wv * 256 + (kgrp * 4 + r) * 16 + c] = ar[r];
      scratch[1024 + wv * 256 + (kgrp * 4 + r) * 16 + c] = az[r];
    }
    __syncthreads();
    if (tid < 128) {
      float rv = (scratch[tid] + scratch[256 + tid]) +
                 (scratch[512 + tid] + scratch[768 + tid]) + b_r;
      float zv = (scratch[1024 + tid] + scratch[1280 + tid]) +
                 (scratch[1536 + tid] + scratch[1792 + tid]) + b_z;
      float rg = 1.f / (1.f + __expf(-rv));
      zt_reg = 1.f / (1.f + __expf(-zv));
      float hrv = hown * rg;
      unsigned short hb = f2bf(hrv);
      unsigned short lb = f2bf(hrv - bf2f(hb));
      st_coh_u32(hr2 + ((size_t)((t & 1) * 64 + 8 * g + bl)) * 512 + C1 + cl,
                 ((u32)hb << 16) | lb);
    }
    asm volatile("s_waitcnt vmcnt(0)" ::: "memory");
    if (wv < 2 && lane == 0) st_coh_u32(myflag, 2 * (u32)t + 1);

    // ================= phase 2: xu pre-GEMM + x(t+1) split (hidden), then hr
    f32x4 au = {0.f, 0.f, 0.f, 0.f};
#pragma unroll
    for (int j = 0; j < 2; ++j) {
      bf16x8 bu = *(const bf16x8*)&wlo[((48 + wv + 4 * j) * 64 + lane) * 8];
      chunk3(xhi[j], xlo[j], wuhi[j], bu, au);
    }
    if (t + 1 < TT) split_x(t + 1);
    poll(2 * (u32)t + 1);
    {
      const u64* hrb = (const u64*)(hr2 + ((size_t)((t & 1) * 64 + 8 * g + arow)) * 512 +
                                    32 * wv + kgrp * 8);
      u64 Q[16];
#pragma unroll
      for (int p = 0; p < 4; ++p) {
        Q[4 * p + 0] = ld_coh_u64(hrb + 64 * p + 0);
        Q[4 * p + 1] = ld_coh_u64(hrb + 64 * p + 1);
        Q[4 * p + 2] = ld_coh_u64(hrb + 64 * p + 2);
        Q[4 * p + 3] = ld_coh_u64(hrb + 64 * p + 3);
      }
#pragma unroll
      for (int p = 0; p < 4; ++p) {
        bf16x8 ahi, alo;
#pragma unroll
        for (int i = 0; i < 4; ++i) {
          u32 lo32 = (u32)Q[4 * p + i], hi32 = (u32)(Q[4 * p + i] >> 32);
          ahi[2 * i] = (short)(lo32 >> 16);
          alo[2 * i] = (short)lo32;
          ahi[2 * i + 1] = (short)(hi32 >> 16);
          alo[2 * i + 1] = (short)hi32;
        }
        const int j = p + 2;
        bf16x8 bu = *(const bf16x8*)&wlo[((48 + wv + 4 * j) * 64 + lane) * 8];
        chunk3(ahi, alo, wuhi[j], bu, au);
      }
    }
    __syncthreads();  // WAR: phase-1 reduce reads done
#pragma unroll
    for (int r = 0; r < 4; ++r)
      scratch[wv * 256 + (kgrp * 4 + r) * 16 + c] = au[r];
    __syncthreads();
    if (tid < 128) {
      float uv = (scratch[tid] + scratch[256 + tid]) +
                 (scratch[512 + tid] + scratch[768 + tid]) + b_u;
      float e = __expf(2.f * uv);
      float th = 1.f - 2.f / (e + 1.f);  // tanh(uv)
      float hn = hown + zt_reg * (th - hown);
      hown = hn;
      unsigned short hb = f2bf(hn);
      unsigned short lb = f2bf(hn - bf2f(hb));
      st_coh_u32(h2 + ((size_t)((t & 1) * 64 + 8 * g + bl)) * 512 + C1 + cl,
                 ((u32)hb << 16) | lb);
      if (t == TT - 1) out[(size_t)(8 * g + bl) * UU + C1 + cl] = hn;
    }
    asm volatile("s_waitcnt vmcnt(0)" ::: "memory");
    if (wv < 2 && lane == 0) st_coh_u32(myflag, 2 * (u32)t + 2);

    // ---- next-step phase-1 x-partials (hidden before next poll)
    ar = (f32x4){0.f, 0.f, 0.f, 0.f};
    az = (f32x4){0.f, 0.f, 0.f, 0.f};
    if (t + 1 < TT) {
#pragma unroll
      for (int j = 0; j < 2; ++j) {
        bf16x8 br = *(const bf16x8*)&wlo[((wv + 4 * j) * 64 + lane) * 8];
        bf16x8 bz = *(const bf16x8*)&wlo[((24 + wv + 4 * j) * 64 + lane) * 8];
        chunk3(xhi[j], xlo[j], wrhi[j], br, ar);
        chunk3(xhi[j], xlo[j], wzhi[j], bz, az);
      }
    }
  }
}

extern "C" void kernel_launch(void* const* d_in, const int* in_sizes, int n_in,
                              void* d_out, int out_size, void* d_ws,
                              size_t ws_size, hipStream_t stream) {
  (void)in_sizes; (void)n_in; (void)out_size; (void)ws_size;
  hipMemsetAsync(d_ws, 0, WS_BYTES, stream);  // h(-1)=0, flags=0 (ready @ t=0)
  gru_persist<<<dim3(256), dim3(256), 0, stream>>>(
      (const float*)d_in[0], (const float*)d_in[1], (const float*)d_in[2],
      (const float*)d_in[3], (const float*)d_in[4], (const float*)d_in[5],
      (const float*)d_in[6], (float*)d_out, (unsigned char*)d_ws);
}